// Round 3
// baseline (197.220 us; speedup 1.0000x reference)
//
#include <hip/hip_runtime.h>

#define BATCH 8
#define NROW  2048
#define NF    64
#define JSPLIT 4
#define JPB   (NROW / JSPLIT)                 // 512 j per block
#define TOT   ((size_t)BATCH * NROW * NF)     // 1048576 outputs

typedef float f32x4 __attribute__((ext_vector_type(4)));

// out[b,i,f] = (sum_j a[b,i,j]*x[b,j,f]) > 0.5 ? 1 : 0
//
// No LDS, no barriers. a-rows are broadcast-merged by the coalescer
// (4 unique 16B addrs per wave-instr); x is L2/L3-resident (4 MB).
// Thread tile 4 rows x 4 cols; f32 accumulate per 32-j chunk, folded
// into f64 masters; f32 partials to ws; combine kernel reduces JSPLIT
// partials in f64 and thresholds.

#define MAD4(ACC, S, XV)                          \
  ACC.x = fmaf((S), (XV).x, ACC.x);               \
  ACC.y = fmaf((S), (XV).y, ACC.y);               \
  ACC.z = fmaf((S), (XV).z, ACC.z);               \
  ACC.w = fmaf((S), (XV).w, ACC.w);

template <bool DIRECT>
__global__ __launch_bounds__(256, 4)
void gemm_nolds(const float* __restrict__ xg,
                const float* __restrict__ ag,
                float* __restrict__ outg,
                float* __restrict__ wsv) {
  const int tid  = threadIdx.x;
  const int colg = tid & 15;           // 16 col-groups * 4 cols
  const int rowg = tid >> 4;           // 16 row-groups * 4 rows
  const int b    = blockIdx.y;
  const int i0   = blockIdx.x * 64;
  const int z    = blockIdx.z;
  const int j0   = DIRECT ? 0 : z * JPB;
  const int r0   = i0 + rowg * 4;
  const int NFOLD = (DIRECT ? NROW : JPB) / 32;   // 32-j folds: 64 or 16

  const float* aB = ag + ((size_t)b * NROW + r0) * NROW + j0;
  const f32x4* a0p = (const f32x4*)(aB);
  const f32x4* a1p = (const f32x4*)(aB + NROW);
  const f32x4* a2p = (const f32x4*)(aB + 2 * (size_t)NROW);
  const f32x4* a3p = (const f32x4*)(aB + 3 * (size_t)NROW);
  const f32x4* xp  = (const f32x4*)(xg + (size_t)b * NROW * NF + (size_t)j0 * NF) + colg;

  double macc[16];
#pragma unroll
  for (int i = 0; i < 16; ++i) macc[i] = 0.0;

  for (int t = 0; t < NFOLD; ++t) {
    f32x4 acc0 = {0.f,0.f,0.f,0.f}, acc1 = {0.f,0.f,0.f,0.f};
    f32x4 acc2 = {0.f,0.f,0.f,0.f}, acc3 = {0.f,0.f,0.f,0.f};
    const f32x4* xt = xp + (size_t)t * 8 * 64;      // 8 j-quads * (4 j * 16)
#pragma unroll
    for (int u = 0; u < 8; ++u) {
      const int jq = t * 8 + u;
      // a: streaming, read-once -> nontemporal (don't evict x from L2)
      f32x4 A0 = __builtin_nontemporal_load(a0p + jq);
      f32x4 A1 = __builtin_nontemporal_load(a1p + jq);
      f32x4 A2 = __builtin_nontemporal_load(a2p + jq);
      f32x4 A3 = __builtin_nontemporal_load(a3p + jq);
      const f32x4* xu = xt + u * 64;
      f32x4 X0 = xu[0];
      f32x4 X1 = xu[16];
      f32x4 X2 = xu[32];
      f32x4 X3 = xu[48];
      MAD4(acc0, A0.x, X0) MAD4(acc0, A0.y, X1) MAD4(acc0, A0.z, X2) MAD4(acc0, A0.w, X3)
      MAD4(acc1, A1.x, X0) MAD4(acc1, A1.y, X1) MAD4(acc1, A1.z, X2) MAD4(acc1, A1.w, X3)
      MAD4(acc2, A2.x, X0) MAD4(acc2, A2.y, X1) MAD4(acc2, A2.z, X2) MAD4(acc2, A2.w, X3)
      MAD4(acc3, A3.x, X0) MAD4(acc3, A3.y, X1) MAD4(acc3, A3.z, X2) MAD4(acc3, A3.w, X3)
    }
    macc[0]  += (double)acc0.x; macc[1]  += (double)acc0.y;
    macc[2]  += (double)acc0.z; macc[3]  += (double)acc0.w;
    macc[4]  += (double)acc1.x; macc[5]  += (double)acc1.y;
    macc[6]  += (double)acc1.z; macc[7]  += (double)acc1.w;
    macc[8]  += (double)acc2.x; macc[9]  += (double)acc2.y;
    macc[10] += (double)acc2.z; macc[11] += (double)acc2.w;
    macc[12] += (double)acc3.x; macc[13] += (double)acc3.y;
    macc[14] += (double)acc3.z; macc[15] += (double)acc3.w;
  }

  if (DIRECT) {
    const size_t obase = ((size_t)b * NROW + r0) * NF + colg * 4;
#pragma unroll
    for (int k = 0; k < 4; ++k) {
      f32x4 o;
      o.x = (macc[k * 4 + 0] > 0.5) ? 1.0f : 0.0f;
      o.y = (macc[k * 4 + 1] > 0.5) ? 1.0f : 0.0f;
      o.z = (macc[k * 4 + 2] > 0.5) ? 1.0f : 0.0f;
      o.w = (macc[k * 4 + 3] > 0.5) ? 1.0f : 0.0f;
      *(f32x4*)(outg + obase + (size_t)k * NF) = o;
    }
  } else {
    float* wbase = wsv + (size_t)z * TOT + ((size_t)b * NROW + r0) * NF + colg * 4;
#pragma unroll
    for (int k = 0; k < 4; ++k) {
      f32x4 o;
      o.x = (float)macc[k * 4 + 0];
      o.y = (float)macc[k * 4 + 1];
      o.z = (float)macc[k * 4 + 2];
      o.w = (float)macc[k * 4 + 3];
      *(f32x4*)(wbase + (size_t)k * NF) = o;
    }
  }
}

__global__ __launch_bounds__(256)
void combine_thresh(const float* __restrict__ wsv, float* __restrict__ outg) {
  const size_t e = ((size_t)blockIdx.x * 256 + threadIdx.x) * 4;
  f32x4 p0 = *(const f32x4*)(wsv + e);
  f32x4 p1 = *(const f32x4*)(wsv + e + TOT);
  f32x4 p2 = *(const f32x4*)(wsv + e + 2 * TOT);
  f32x4 p3 = *(const f32x4*)(wsv + e + 3 * TOT);
  f32x4 o;
  o.x = (((double)p0.x + p1.x + p2.x + p3.x) > 0.5) ? 1.0f : 0.0f;
  o.y = (((double)p0.y + p1.y + p2.y + p3.y) > 0.5) ? 1.0f : 0.0f;
  o.z = (((double)p0.z + p1.z + p2.z + p3.z) > 0.5) ? 1.0f : 0.0f;
  o.w = (((double)p0.w + p1.w + p2.w + p3.w) > 0.5) ? 1.0f : 0.0f;
  *(f32x4*)(outg + e) = o;
}

extern "C" void kernel_launch(void* const* d_in, const int* in_sizes, int n_in,
                              void* d_out, int out_size, void* d_ws, size_t ws_size,
                              hipStream_t stream) {
  const float* x = (const float*)d_in[0];
  const float* a = (const float*)d_in[1];
  float* out = (float*)d_out;
  float* ws = (float*)d_ws;

  const size_t need = (size_t)JSPLIT * TOT * sizeof(float);   // 16 MB
  if (ws_size >= need) {
    dim3 grid(NROW / 64, BATCH, JSPLIT);
    gemm_nolds<false><<<grid, dim3(256), 0, stream>>>(x, a, out, ws);
    combine_thresh<<<dim3((unsigned)(TOT / 1024)), dim3(256), 0, stream>>>(ws, out);
  } else {
    dim3 grid(NROW / 64, BATCH, 1);
    gemm_nolds<true><<<grid, dim3(256), 0, stream>>>(x, a, out, ws);
  }
}

// Round 4
// 110.193 us; speedup vs baseline: 1.7898x; 1.7898x over previous
//
#include <hip/hip_runtime.h>

#define BATCH 8
#define NROW  2048
#define NF    64
#define JSPLIT 4
#define JPB   (NROW / JSPLIT)               // 512 j per block (split path)
#define CHUNK 32
#define TOT   ((size_t)BATCH * NROW * NF)   // 1048576 = xT floats = out elems

typedef float f32x4 __attribute__((ext_vector_type(4)));
typedef float f32x8 __attribute__((ext_vector_type(8)));

#define AS1 __attribute__((address_space(1)))
#define AS3 __attribute__((address_space(3)))

__device__ __forceinline__ void gld16(const float* g, float* l) {
  __builtin_amdgcn_global_load_lds((const AS1 void*)g, (AS3 void*)l, 16, 0, 0);
}

// ---- pass 1: xT[b][f][j] = x[b][j][f]  (padded-LDS tile transpose) ----
__global__ __launch_bounds__(256, 4)
void transpose_x(const float* __restrict__ xg, float* __restrict__ xt) {
  __shared__ float t[64][65];
  const int b  = blockIdx.y;
  const int j0 = blockIdx.x * 64;
  const int l  = threadIdx.x & 63;
  const int g  = threadIdx.x >> 6;
  const float* src = xg + ((size_t)b * NROW + j0) * NF;
#pragma unroll
  for (int k = 0; k < 16; ++k) {
    const int j = g * 16 + k;
    t[j][l] = src[(size_t)j * NF + l];          // coalesced read, lane=f
  }
  __syncthreads();
  float* dst = xt + (size_t)b * (NROW * NF) + j0;
#pragma unroll
  for (int k = 0; k < 16; ++k) {
    const int f = g * 16 + k;
    dst[(size_t)f * NROW + l] = t[l][f];        // coalesced write, lane=j
  }
}

// ---- pass 2: GEMM. lane=f, wave owns 8 rows; a via scalar loads;
//      xT chunk [64 f][32 j] in LDS, quad-swizzled, double-buffered. ----
template <bool DIRECT>
__global__ __launch_bounds__(256, 6)
void gemm_smem(const float* __restrict__ ag, const float* __restrict__ xt,
               float* __restrict__ outg, float* __restrict__ wpart) {
  __shared__ __align__(16) float sX[2][NF * CHUNK];   // 2 x 8KB

  const int tid = threadIdx.x;
  const int f   = tid & 63;
  const int wv  = __builtin_amdgcn_readfirstlane(tid >> 6);   // wave id, uniform
  const int b   = blockIdx.z;
  const int i0  = blockIdx.x * 32 + wv * 8;    // wave's first row
  const int z   = DIRECT ? 0 : blockIdx.y;
  const int jbase = z * (DIRECT ? 0 : JPB);
  const int nch = (DIRECT ? NROW : JPB) / CHUNK;
  const int key = f & 7;

  const float* aW = ag + ((size_t)b * NROW + i0) * NROW;   // wave-uniform base
  const float* xb = xt + (size_t)b * (NROW * NF);

  // stage chunk j0 into sX[buf]: 2 rounds x 256 slots; slot s -> row fr=s>>3,
  // lds quad-pos p=s&7 holds global quad q = p ^ (fr&7)  (linear dest,
  // inverse-swizzled source; read applies the same XOR)
  auto stage = [&](int buf, int j0) {
#pragma unroll
    for (int r = 0; r < 2; ++r) {
      const int s  = r * 256 + tid;
      const int fr = s >> 3;
      const int q  = (s & 7) ^ (fr & 7);
      gld16(xb + (size_t)fr * NROW + j0 + q * 4,
            &sX[buf][0] + r * 1024 + wv * 256);
    }
  };

  float acc[8];
  double macc[8];
#pragma unroll
  for (int r = 0; r < 8; ++r) { acc[r] = 0.f; macc[r] = 0.0; }

  stage(0, jbase);

  for (int t = 0; t < nch; ++t) {
    __syncthreads();                      // drains gld_lds of chunk t
    if (t + 1 < nch) stage((t + 1) & 1, jbase + (t + 1) * CHUNK);

    const float* sXb = &sX[t & 1][0];
    const int j0 = jbase + t * CHUNK;
#pragma unroll
    for (int g = 0; g < 4; ++g) {         // 8 j per group
      const f32x4 x0 = *(const f32x4*)&sXb[f * 32 + (((2 * g) ^ key) << 2)];
      const f32x4 x1 = *(const f32x4*)&sXb[f * 32 + (((2 * g + 1) ^ key) << 2)];
#pragma unroll
      for (int r = 0; r < 8; ++r) {
        // wave-uniform 32B load -> s_load_dwordx8 (scalar pipe)
        const f32x8 av = *(const f32x8*)(aW + (size_t)r * NROW + j0 + g * 8);
        float s = acc[r];
        s = fmaf(av[0], x0.x, s); s = fmaf(av[1], x0.y, s);
        s = fmaf(av[2], x0.z, s); s = fmaf(av[3], x0.w, s);
        s = fmaf(av[4], x1.x, s); s = fmaf(av[5], x1.y, s);
        s = fmaf(av[6], x1.z, s); s = fmaf(av[7], x1.w, s);
        acc[r] = s;
      }
    }
#pragma unroll
    for (int r = 0; r < 8; ++r) { macc[r] += (double)acc[r]; acc[r] = 0.f; }
  }

  if (DIRECT) {
#pragma unroll
    for (int r = 0; r < 8; ++r)
      outg[((size_t)b * NROW + i0 + r) * NF + f] = (macc[r] > 0.5) ? 1.0f : 0.0f;
  } else {
    float* wb = wpart + (size_t)z * TOT + ((size_t)b * NROW + i0) * NF + f;
#pragma unroll
    for (int r = 0; r < 8; ++r)
      wb[(size_t)r * NF] = (float)macc[r];
  }
}

// ---- pass 3: reduce JSPLIT partials in f64, threshold ----
__global__ __launch_bounds__(256)
void combine_thresh(const float* __restrict__ wsv, float* __restrict__ outg) {
  const size_t e = ((size_t)blockIdx.x * 256 + threadIdx.x) * 4;
  f32x4 p0 = *(const f32x4*)(wsv + e);
  f32x4 p1 = *(const f32x4*)(wsv + e + TOT);
  f32x4 p2 = *(const f32x4*)(wsv + e + 2 * TOT);
  f32x4 p3 = *(const f32x4*)(wsv + e + 3 * TOT);
  f32x4 o;
  o.x = (((double)p0.x + p1.x + p2.x + p3.x) > 0.5) ? 1.0f : 0.0f;
  o.y = (((double)p0.y + p1.y + p2.y + p3.y) > 0.5) ? 1.0f : 0.0f;
  o.z = (((double)p0.z + p1.z + p2.z + p3.z) > 0.5) ? 1.0f : 0.0f;
  o.w = (((double)p0.w + p1.w + p2.w + p3.w) > 0.5) ? 1.0f : 0.0f;
  *(f32x4*)(outg + e) = o;
}

extern "C" void kernel_launch(void* const* d_in, const int* in_sizes, int n_in,
                              void* d_out, int out_size, void* d_ws, size_t ws_size,
                              hipStream_t stream) {
  const float* x = (const float*)d_in[0];
  const float* a = (const float*)d_in[1];
  float* out = (float*)d_out;
  float* xT  = (float*)d_ws;                 // [0, TOT) floats
  float* wp  = (float*)d_ws + TOT;           // JSPLIT * TOT floats

  transpose_x<<<dim3(NROW / 64, BATCH), dim3(256), 0, stream>>>(x, xT);

  const size_t need = (size_t)(1 + JSPLIT) * TOT * sizeof(float);   // 20 MB
  if (ws_size >= need) {
    gemm_smem<false><<<dim3(NROW / 32, JSPLIT, BATCH), dim3(256), 0, stream>>>(
        a, xT, out, wp);
    combine_thresh<<<dim3((unsigned)(TOT / 1024)), dim3(256), 0, stream>>>(wp, out);
  } else {
    gemm_smem<true><<<dim3(NROW / 32, 1, BATCH), dim3(256), 0, stream>>>(
        a, xT, out, nullptr);
  }
}

// Round 5
// 107.466 us; speedup vs baseline: 1.8352x; 1.0254x over previous
//
#include <hip/hip_runtime.h>

#define BATCH 8
#define NROW  2048
#define NF    64
#define JSPLIT 4
#define JPB   (NROW / JSPLIT)               // 512 j per block (split path)
#define CHUNK 32
#define NCH   (JPB / CHUNK)                 // 16
#define TOT   ((size_t)BATCH * NROW * NF)   // 1048576

typedef float  f32x4  __attribute__((ext_vector_type(4)));
typedef __bf16 bf16x8 __attribute__((ext_vector_type(8)));
typedef unsigned short u16x8 __attribute__((ext_vector_type(8)));

union frag_cast { u16x8 u; bf16x8 b; };

#define AS1 __attribute__((address_space(1)))
#define AS3 __attribute__((address_space(3)))

__device__ __forceinline__ void gld16(const float* g, float* l) {
  __builtin_amdgcn_global_load_lds((const AS1 void*)g, (AS3 void*)l, 16, 0, 0);
}
__device__ __forceinline__ float ubits(unsigned u) {
  union { unsigned u; float f; } c; c.u = u; return c.f;
}
__device__ __forceinline__ unsigned fbits(float f) {
  union { float f; unsigned u; } c; c.f = f; return c.u;
}

// ---- pass 1: transpose x and split into 3 bf16 levels: xs[lvl][b][f][j] ----
// x = up(x0) + up(x1) + up(x2) with x0,x1 truncation splits (exact) and x2 RNE.
__global__ __launch_bounds__(256, 4)
void prep_x(const float* __restrict__ xg, unsigned short* __restrict__ xs) {
  __shared__ float t[64][65];
  const int b  = blockIdx.y;
  const int j0 = blockIdx.x * 64;
  const int l  = threadIdx.x & 63;
  const int g  = threadIdx.x >> 6;
  const float* src = xg + ((size_t)b * NROW + j0) * NF;
#pragma unroll
  for (int k = 0; k < 16; ++k) {
    const int j = g * 16 + k;
    t[j][l] = src[(size_t)j * NF + l];
  }
  __syncthreads();
#pragma unroll
  for (int k = 0; k < 16; ++k) {
    const int f = g * 16 + k;
    const float v = t[l][f];
    const unsigned u0 = fbits(v);
    const float f0 = ubits(u0 & 0xFFFF0000u);
    const float r  = v - f0;                       // exact
    const unsigned u1 = fbits(r);
    const float f1 = ubits(u1 & 0xFFFF0000u);
    const float r2 = r - f1;                       // exact
    const unsigned u2 = fbits(r2);
    const unsigned short s2 =
        (unsigned short)((u2 + 0x7FFFu + ((u2 >> 16) & 1u)) >> 16);  // RNE
    const size_t o = ((size_t)b * NF + f) * NROW + j0 + l;
    xs[o]           = (unsigned short)(u0 >> 16);
    xs[o + TOT]     = (unsigned short)(u1 >> 16);
    xs[o + 2 * TOT] = s2;
  }
}

// ---- pass 2: split-bf16 MFMA GEMM ----
// Block: 256 thr (4 waves), tile 64 rows x 64 f.  Wave: 16 rows, 4 n-tiles.
// a staged via global_load_lds (quad-XOR pre-swizzled source), split to 3
// bf16 A-frags in-register.  B-frags read direct from xs (L2-resident).
// 6-term product chain per n-tile per 32-j chunk; f64 fold per chunk.
template <bool DIRECT>
__global__ __launch_bounds__(256, 4)
void gemm_mfma(const float* __restrict__ ag, const unsigned short* __restrict__ xs,
               float* __restrict__ outg, float* __restrict__ wp) {
  __shared__ __align__(16) float sA[2][64 * CHUNK];   // 2 x 8KB

  const int tid  = threadIdx.x;
  const int ln   = tid & 63;
  const int wv   = tid >> 6;
  const int ln15 = ln & 15;            // A row within wave-tile / B col / D col
  const int g    = ln >> 4;            // k-group (A/B), row-group (D)
  const int key  = ln15 & 7;
  const int b    = blockIdx.z;
  const int i0   = blockIdx.x * 64;
  const int z    = DIRECT ? 0 : blockIdx.y;
  const int jb   = z * (DIRECT ? 0 : JPB);
  const int nch  = DIRECT ? (NROW / CHUNK) : NCH;

  const float* aB = ag + ((size_t)b * NROW + i0) * NROW;
  // B base: lane ln15 = col n, k-offset g*8 (8 contiguous bf16 = 16B)
  const unsigned short* xbase =
      xs + ((size_t)b * NF + ln15) * NROW + jb + g * 8;

  // stage a-chunk [64 rows][32 k] f32, quad position p holds global quad
  // p ^ (row&7) (linear LDS dest, inverse-swizzled global source)
  auto stage = [&](int buf, int j0) {
#pragma unroll
    for (int r = 0; r < 2; ++r) {
      const int s   = r * 256 + tid;
      const int row = s >> 3;
      const int q   = (s & 7) ^ (row & 7);
      gld16(aB + (size_t)row * NROW + j0 + q * 4,
            &sA[buf][0] + (r * 256 + wv * 64) * 4);
    }
  };

  double macc[4][4];
#pragma unroll
  for (int i = 0; i < 4; ++i)
#pragma unroll
    for (int j = 0; j < 4; ++j) macc[i][j] = 0.0;

  stage(0, jb);

  for (int t = 0; t < nch; ++t) {
    __syncthreads();
    if (t + 1 < nch) stage((t + 1) & 1, jb + (t + 1) * CHUNK);

    // ---- A: 8 f32 (k = g*8..+8) from swizzled LDS, split to 3 bf16 frags ----
    const float* sAb = &sA[t & 1][0];
    const int rowOff = (wv * 16 + ln15) * 8;
    const f32x4 q0 = *(const f32x4*)(sAb + (rowOff + ((2 * g) ^ key)) * 4);
    const f32x4 q1 = *(const f32x4*)(sAb + (rowOff + ((2 * g + 1) ^ key)) * 4);
    float av[8];
    *(f32x4*)&av[0] = q0;
    *(f32x4*)&av[4] = q1;
    u16x8 h0, h1, h2;
#pragma unroll
    for (int e = 0; e < 8; ++e) {
      const unsigned u0 = fbits(av[e]);
      const float f0 = ubits(u0 & 0xFFFF0000u);
      const float r  = av[e] - f0;
      const unsigned u1 = fbits(r);
      const float f1 = ubits(u1 & 0xFFFF0000u);
      const float r2 = r - f1;
      const unsigned u2 = fbits(r2);
      h0[e] = (unsigned short)(u0 >> 16);
      h1[e] = (unsigned short)(u1 >> 16);
      h2[e] = (unsigned short)((u2 + 0x7FFFu + ((u2 >> 16) & 1u)) >> 16);
    }
    frag_cast A0, A1, A2;
    A0.u = h0; A1.u = h1; A2.u = h2;

    // ---- 4 n-tiles in 2 register-groups of 2 (keeps VGPR < 128) ----
#pragma unroll
    for (int ng = 0; ng < 2; ++ng) {
      frag_cast Bf[2][3];
#pragma unroll
      for (int nn = 0; nn < 2; ++nn) {
        const int nt = ng * 2 + nn;
        const unsigned short* xp = xbase + (size_t)nt * 16 * NROW + t * CHUNK;
#pragma unroll
        for (int lvl = 0; lvl < 3; ++lvl)
          Bf[nn][lvl].u = *(const u16x8*)(xp + (size_t)lvl * TOT);
      }
#pragma unroll
      for (int nn = 0; nn < 2; ++nn) {
        const int nt = ng * 2 + nn;
        f32x4 c = {0.f, 0.f, 0.f, 0.f};
        c = __builtin_amdgcn_mfma_f32_16x16x32_bf16(A2.b, Bf[nn][0].b, c, 0, 0, 0);
        c = __builtin_amdgcn_mfma_f32_16x16x32_bf16(A0.b, Bf[nn][2].b, c, 0, 0, 0);
        c = __builtin_amdgcn_mfma_f32_16x16x32_bf16(A1.b, Bf[nn][1].b, c, 0, 0, 0);
        c = __builtin_amdgcn_mfma_f32_16x16x32_bf16(A1.b, Bf[nn][0].b, c, 0, 0, 0);
        c = __builtin_amdgcn_mfma_f32_16x16x32_bf16(A0.b, Bf[nn][1].b, c, 0, 0, 0);
        c = __builtin_amdgcn_mfma_f32_16x16x32_bf16(A0.b, Bf[nn][0].b, c, 0, 0, 0);
        macc[nt][0] += (double)c.x;
        macc[nt][1] += (double)c.y;
        macc[nt][2] += (double)c.z;
        macc[nt][3] += (double)c.w;
      }
    }
  }

  // ---- epilogue: D row = g*4 + reg, col = nt*16 + ln15 ----
  if (DIRECT) {
#pragma unroll
    for (int nt = 0; nt < 4; ++nt)
#pragma unroll
      for (int r = 0; r < 4; ++r)
        outg[((size_t)b * NROW + i0 + wv * 16 + g * 4 + r) * NF + nt * 16 + ln15] =
            (macc[nt][r] > 0.5) ? 1.0f : 0.0f;
  } else {
    float* wb = wp + (size_t)z * TOT;
#pragma unroll
    for (int nt = 0; nt < 4; ++nt)
#pragma unroll
      for (int r = 0; r < 4; ++r)
        wb[((size_t)b * NROW + i0 + wv * 16 + g * 4 + r) * NF + nt * 16 + ln15] =
            (float)macc[nt][r];
  }
}

// ---- pass 3: reduce JSPLIT partials in f64, threshold ----
__global__ __launch_bounds__(256)
void combine_thresh(const float* __restrict__ wsv, float* __restrict__ outg) {
  const size_t e = ((size_t)blockIdx.x * 256 + threadIdx.x) * 4;
  f32x4 p0 = *(const f32x4*)(wsv + e);
  f32x4 p1 = *(const f32x4*)(wsv + e + TOT);
  f32x4 p2 = *(const f32x4*)(wsv + e + 2 * TOT);
  f32x4 p3 = *(const f32x4*)(wsv + e + 3 * TOT);
  f32x4 o;
  o.x = (((double)p0.x + p1.x + p2.x + p3.x) > 0.5) ? 1.0f : 0.0f;
  o.y = (((double)p0.y + p1.y + p2.y + p3.y) > 0.5) ? 1.0f : 0.0f;
  o.z = (((double)p0.z + p1.z + p2.z + p3.z) > 0.5) ? 1.0f : 0.0f;
  o.w = (((double)p0.w + p1.w + p2.w + p3.w) > 0.5) ? 1.0f : 0.0f;
  *(f32x4*)(outg + e) = o;
}

extern "C" void kernel_launch(void* const* d_in, const int* in_sizes, int n_in,
                              void* d_out, int out_size, void* d_ws, size_t ws_size,
                              hipStream_t stream) {
  const float* x = (const float*)d_in[0];
  const float* a = (const float*)d_in[1];
  float* out = (float*)d_out;
  unsigned short* xs = (unsigned short*)d_ws;                 // 3*TOT u16 = 6 MB
  float* wp = (float*)((char*)d_ws + 3 * TOT * sizeof(unsigned short));

  prep_x<<<dim3(NROW / 64, BATCH), dim3(256), 0, stream>>>(x, xs);

  const size_t need = 3 * TOT * sizeof(unsigned short)
                    + (size_t)JSPLIT * TOT * sizeof(float);   // 22 MB
  if (ws_size >= need) {
    gemm_mfma<false><<<dim3(NROW / 64, JSPLIT, BATCH), dim3(256), 0, stream>>>(
        a, xs, out, wp);
    combine_thresh<<<dim3((unsigned)(TOT / 1024)), dim3(256), 0, stream>>>(wp, out);
  } else {
    gemm_mfma<true><<<dim3(NROW / 64, 1, BATCH), dim3(256), 0, stream>>>(
        a, xs, out, nullptr);
  }
}